// Round 1
// baseline (1265.558 us; speedup 1.0000x reference)
//
#include <hip/hip_runtime.h>
#include <cstdint>
#include <cstddef>

typedef unsigned short u16;
typedef __bf16 bf16x8 __attribute__((ext_vector_type(8)));
typedef float f32x4 __attribute__((ext_vector_type(4)));

// ---------- helpers ----------
__device__ __forceinline__ u16 f2bf(float f) {            // round-to-nearest-even
  unsigned u = __float_as_uint(f);
  u += 0x7fffu + ((u >> 16) & 1u);
  return (u16)(u >> 16);
}
__device__ __forceinline__ float bf2f(u16 s) {
  return __uint_as_float(((unsigned)s) << 16);
}

// async global->LDS, 16B per lane; HW dest = wave-uniform base + lane*16.
// Per-lane lds ptr where lane l's value == base + l*16 is equivalent (lane0 = base).
__device__ __forceinline__ void gld16(const void* g, void* l) {
  __builtin_amdgcn_global_load_lds((const __attribute__((address_space(1))) void*)g,
                                   (__attribute__((address_space(3))) void*)l,
                                   16, 0, 0);
}

__device__ __forceinline__ float block_sum(float v, float* sbuf, int tid) {
#pragma unroll
  for (int off = 1; off < 64; off <<= 1) v += __shfl_xor(v, off, 64);
  if ((tid & 63) == 0) sbuf[tid >> 6] = v;
  __syncthreads();
  v = sbuf[0] + sbuf[1] + sbuf[2] + sbuf[3];
  __syncthreads();
  return v;
}
__device__ __forceinline__ float block_max(float v, float* sbuf, int tid) {
#pragma unroll
  for (int off = 1; off < 64; off <<= 1) v = fmaxf(v, __shfl_xor(v, off, 64));
  if ((tid & 63) == 0) sbuf[tid >> 6] = v;
  __syncthreads();
  v = fmaxf(fmaxf(sbuf[0], sbuf[1]), fmaxf(sbuf[2], sbuf[3]));
  __syncthreads();
  return v;
}

// ---------- generic batched NT GEMM ----------
// C[z][m][n] = sum_k A[z][m][k] * B[z][n][k]   (both operands K-major, row stride == K)
// mode 0: fp32 out (+bias[n] if bias)(+res[m*ldc+n] if res)
// mode 1: bf16 out
// mode 2: bf16 out = gelu(acc + bias[n])  (exact erf gelu)
__global__ __launch_bounds__(256) void gemm_nt(
    const u16* __restrict__ A, long long sAz,
    const u16* __restrict__ B, long long sBz,
    const float* __restrict__ bias, const float* __restrict__ res,
    void* __restrict__ out, long long sCz, int ldc,
    int M, int N, int K, int mode)
{
  __shared__ __align__(16) u16 As[128 * 32];
  __shared__ __align__(16) u16 Bs[128 * 32];
  const int tid = threadIdx.x;
  const int z = blockIdx.z;
  const u16* Az = A + (size_t)z * (size_t)sAz;
  const u16* Bz = B + (size_t)z * (size_t)sBz;
  const int m0 = blockIdx.y * 128, n0 = blockIdx.x * 128;
  const int lane = tid & 63, wave = tid >> 6;
  const int wm = (wave >> 1) * 64, wn = (wave & 1) * 64;

  // staging: 512 chunks of 8 bf16 (16B) per tile; 2 insts/thread/tile
  const int c0 = tid, c1 = tid + 256;
  const int ar0 = c0 >> 2, ak0 = (c0 & 3) * 8;
  const int ar1 = c1 >> 2, ak1 = (c1 & 3) * 8;
  int bn0 = n0 + ar0; if (bn0 > N - 1) bn0 = N - 1;   // clamp (garbage rows never stored)
  int bn1 = n0 + ar1; if (bn1 > N - 1) bn1 = N - 1;
  const size_t aoff0 = (size_t)(m0 + ar0) * K + ak0;
  const size_t aoff1 = (size_t)(m0 + ar1) * K + ak1;
  const size_t boff0 = (size_t)bn0 * K + ak0;
  const size_t boff1 = (size_t)bn1 * K + ak1;

  f32x4 acc[4][4] = {};

  for (int k0 = 0; k0 < K; k0 += 32) {
    gld16(Az + aoff0 + k0, As + (size_t)c0 * 8);
    gld16(Az + aoff1 + k0, As + (size_t)c1 * 8);
    gld16(Bz + boff0 + k0, Bs + (size_t)c0 * 8);
    gld16(Bz + boff1 + k0, Bs + (size_t)c1 * 8);
    __syncthreads();                    // compiler emits vmcnt(0) drain before barrier
    bf16x8 af[4], bg[4];
#pragma unroll
    for (int i = 0; i < 4; i++) {
      af[i] = *(const bf16x8*)(As + (wm + i * 16 + (lane & 15)) * 32 + (lane >> 4) * 8);
      bg[i] = *(const bf16x8*)(Bs + (wn + i * 16 + (lane & 15)) * 32 + (lane >> 4) * 8);
    }
#pragma unroll
    for (int i = 0; i < 4; i++)
#pragma unroll
      for (int j = 0; j < 4; j++)
        acc[i][j] = __builtin_amdgcn_mfma_f32_16x16x32_bf16(af[i], bg[j], acc[i][j], 0, 0, 0);
    __syncthreads();
  }

  float* outF = (float*)out;
  u16* outU = (u16*)out;
  const size_t cbase = (size_t)z * (size_t)sCz;
#pragma unroll
  for (int i = 0; i < 4; i++) {
#pragma unroll
    for (int j = 0; j < 4; j++) {
      const int col = n0 + wn + j * 16 + (lane & 15);
      if (col < N) {
#pragma unroll
        for (int r = 0; r < 4; r++) {
          const int gm = m0 + wm + i * 16 + (lane >> 4) * 4 + r;   // M always %128==0
          const size_t idx = cbase + (size_t)gm * ldc + col;
          float v = acc[i][j][r];
          if (mode == 0) {
            if (bias) v += bias[col];
            if (res)  v += res[(size_t)gm * ldc + col];
            outF[idx] = v;
          } else if (mode == 1) {
            outU[idx] = f2bf(v);
          } else {
            v += bias[col];
            v = 0.5f * v * (1.0f + erff(v * 0.70710678118654752f));
            outU[idx] = f2bf(v);
          }
        }
      }
    }
  }
}

// ---------- layernorm (row=1024) -> bf16 ----------
__global__ __launch_bounds__(256) void ln_kernel(const float* __restrict__ x,
    const float* __restrict__ w, const float* __restrict__ b, u16* __restrict__ out)
{
  __shared__ float sbuf[4];
  const int row = blockIdx.x, tid = threadIdx.x;
  const float4 v = *(const float4*)(x + (size_t)row * 1024 + tid * 4);
  float s = block_sum(v.x + v.y + v.z + v.w, sbuf, tid);
  const float u = s * (1.0f / 1024.0f);
  const float d0 = v.x - u, d1 = v.y - u, d2 = v.z - u, d3 = v.w - u;
  float sq = block_sum(d0 * d0 + d1 * d1 + d2 * d2 + d3 * d3, sbuf, tid);
  const float rstd = rsqrtf(sq * (1.0f / 1024.0f) + 1e-12f);
  const int c = tid * 4;
  ushort4 o;
  o.x = f2bf(w[c + 0] * d0 * rstd + b[c + 0]);
  o.y = f2bf(w[c + 1] * d1 * rstd + b[c + 1]);
  o.z = f2bf(w[c + 2] * d2 * rstd + b[c + 2]);
  o.w = f2bf(w[c + 3] * d3 * rstd + b[c + 3]);
  *(ushort4*)(out + (size_t)row * 1024 + c) = o;
}

// ---------- softmax over bf16 score rows (in place), T=1024 ----------
// causal=1: cols > row masked (matches scores*mask-10000*(1-mask): exp underflows to 0)
// causal=0: adds amask[b*1024+col]  (b = (zbase+zi)/16)
__global__ __launch_bounds__(256) void softmax_kernel(u16* __restrict__ sc,
    const float* __restrict__ amask, int zbase, int causal)
{
  __shared__ float sbuf[4];
  const int srow = blockIdx.x, zi = blockIdx.y, tid = threadIdx.x;
  u16* row = sc + ((size_t)zi * 1024 + srow) * 1024;
  const int c = tid * 4;
  ushort4 pk = *(const ushort4*)(row + c);
  float v0 = bf2f(pk.x), v1 = bf2f(pk.y), v2 = bf2f(pk.z), v3 = bf2f(pk.w);
  if (causal) {
    v0 = (c + 0 <= srow) ? v0 : -3.0e38f;
    v1 = (c + 1 <= srow) ? v1 : -3.0e38f;
    v2 = (c + 2 <= srow) ? v2 : -3.0e38f;
    v3 = (c + 3 <= srow) ? v3 : -3.0e38f;
  } else {
    const float* mrow = amask + (size_t)((zbase + zi) >> 4) * 1024;
    v0 += mrow[c + 0]; v1 += mrow[c + 1]; v2 += mrow[c + 2]; v3 += mrow[c + 3];
  }
  const float m = block_max(fmaxf(fmaxf(v0, v1), fmaxf(v2, v3)), sbuf, tid);
  const float e0 = expf(v0 - m), e1 = expf(v1 - m), e2 = expf(v2 - m), e3 = expf(v3 - m);
  const float t = block_sum(e0 + e1 + e2 + e3, sbuf, tid);
  const float inv = 1.0f / t;
  pk.x = f2bf(e0 * inv); pk.y = f2bf(e1 * inv); pk.z = f2bf(e2 * inv); pk.w = f2bf(e3 * inv);
  *(ushort4*)(row + c) = pk;
}

// ---------- weight fp32[K,N] -> bf16 transposed [N,K] ----------
__global__ __launch_bounds__(256) void wconv_kernel(const float* __restrict__ w,
    u16* __restrict__ wt, int K, int N)
{
  __shared__ float t[32][33];
  const int n0 = blockIdx.x * 32, k0 = blockIdx.y * 32;
  const int tx = threadIdx.x & 31, ty = threadIdx.x >> 5;
#pragma unroll
  for (int r = ty; r < 32; r += 8) t[r][tx] = w[(size_t)(k0 + r) * N + n0 + tx];
  __syncthreads();
#pragma unroll
  for (int r = ty; r < 32; r += 8) wt[(size_t)(n0 + r) * K + k0 + tx] = f2bf(t[tx][r]);
}

// ---------- fp32 -> bf16 elementwise (4M elems exactly) ----------
__global__ __launch_bounds__(256) void cvt_kernel(const float* __restrict__ in, u16* __restrict__ out) {
  const size_t i = ((size_t)blockIdx.x * 256 + threadIdx.x) * 4;
  const float4 v = *(const float4*)(in + i);
  ushort4 o; o.x = f2bf(v.x); o.y = f2bf(v.y); o.z = f2bf(v.z); o.w = f2bf(v.w);
  *(ushort4*)(out + i) = o;
}

// ---------- head-split kernels (biases already added by GEMM epilogue) ----------
// qkv scratch [4096,3072] -> qh (scaled 1/8), kh  (v handled by vtrans)
__global__ __launch_bounds__(256) void split_qk_kernel(const float* __restrict__ src,
    u16* __restrict__ qh, u16* __restrict__ kh)
{
  const int n = blockIdx.x * 256 + threadIdx.x;  // 0..2047
  const int m = blockIdx.y;                      // 0..4095
  const float v = src[(size_t)m * 3072 + n];
  const int which = n >> 10, r = n & 1023, h = r >> 6, d = r & 63;
  const int b = m >> 10, s = m & 1023;
  const size_t o = ((size_t)((b * 16 + h) * 1024 + s)) * 64 + d;
  if (which == 0) qh[o] = f2bf(v * 0.125f);
  else            kh[o] = f2bf(v);
}
__global__ __launch_bounds__(256) void split_q_kernel(const float* __restrict__ src, u16* __restrict__ qh) {
  const int n = blockIdx.x * 256 + threadIdx.x;  // 0..1023
  const int m = blockIdx.y;
  const int h = n >> 6, d = n & 63, b = m >> 10, s = m & 1023;
  qh[((size_t)((b * 16 + h) * 1024 + s)) * 64 + d] = f2bf(src[(size_t)m * 1024 + n] * 0.125f);
}
__global__ __launch_bounds__(256) void split_k_kernel(const float* __restrict__ src, u16* __restrict__ kh) {
  const int n = blockIdx.x * 256 + threadIdx.x;  // 0..1023
  const int m = blockIdx.y;
  const int h = n >> 6, d = n & 63, b = m >> 10, s = m & 1023;
  kh[((size_t)((b * 16 + h) * 1024 + s)) * 64 + d] = f2bf(src[(size_t)m * 2048 + n]);
}
// v columns of scratch -> vht[z=bh][d][t]  (transposed for NT ctx-GEMM), LDS tile transpose
__global__ __launch_bounds__(256) void vtrans_kernel(const float* __restrict__ src,
    int src_ld, int col_off, u16* __restrict__ vht)
{
  __shared__ float t[32][33];
  const int z = blockIdx.z, b = z >> 4, h = z & 15;
  const int s0 = blockIdx.y * 32, d0 = blockIdx.x * 32;
  const int tx = threadIdx.x & 31, ty = threadIdx.x >> 5;
#pragma unroll
  for (int r = ty; r < 32; r += 8)
    t[r][tx] = src[(size_t)(b * 1024 + s0 + r) * src_ld + col_off + h * 64 + d0 + tx];
  __syncthreads();
#pragma unroll
  for (int r = ty; r < 32; r += 8)
    vht[((size_t)z * 64 + d0 + r) * 1024 + s0 + tx] = f2bf(t[tx][r]);
}

// ---------- workspace layout (bytes) ----------
constexpr size_t WT_QKV    = 0;
constexpr size_t WT_ATTN_O = WT_QKV    + 3072ULL * 1024 * 2;
constexpr size_t WT_Q      = WT_ATTN_O + 1024ULL * 1024 * 2;
constexpr size_t WT_KV     = WT_Q      + 1024ULL * 1024 * 2;
constexpr size_t WT_CA_O   = WT_KV     + 2048ULL * 1024 * 2;
constexpr size_t WT_FFN_IN = WT_CA_O   + 1024ULL * 1024 * 2;
constexpr size_t WT_FFN_OUT= WT_FFN_IN + 4096ULL * 1024 * 2;
constexpr size_t ENC_BF    = WT_FFN_OUT+ 4096ULL * 1024 * 2;
constexpr size_t XLN       = ENC_BF    + 4096ULL * 1024 * 2;
constexpr size_t QH        = XLN       + 4096ULL * 1024 * 2;
constexpr size_t KH        = QH        + 64ULL * 1024 * 64 * 2;
constexpr size_t VHT       = KH        + 64ULL * 1024 * 64 * 2;
constexpr size_t CTX       = VHT       + 64ULL * 1024 * 64 * 2;
constexpr size_t SCORES    = CTX       + 4096ULL * 1024 * 2;          // 16 heads * 1M bf16
constexpr size_t HBUF      = SCORES    + 16ULL * 1024 * 1024 * 2;
constexpr size_t SCRATCH   = HBUF      + 4096ULL * 1024 * 4;          // fp32 gemm scratch (48MB); ffn_mid bf16 overlays
// total = SCRATCH + 4096*3072*4 = 176 MB

extern "C" void kernel_launch(void* const* d_in, const int* in_sizes, int n_in,
                              void* d_out, int out_size, void* d_ws, size_t ws_size,
                              hipStream_t stream) {
  const float* hidden   = (const float*)d_in[0];
  const float* enc      = (const float*)d_in[1];
  const float* encm     = (const float*)d_in[2];
  // d_in[3] dec_attn_mask: causal tril, applied analytically in softmax
  const float* ln1w = (const float*)d_in[4],  *ln1b = (const float*)d_in[5];
  const float* qkv_w = (const float*)d_in[6], *qkv_b = (const float*)d_in[7];
  const float* attn_o_w = (const float*)d_in[8], *attn_o_b = (const float*)d_in[9];
  const float* ln2w = (const float*)d_in[10], *ln2b = (const float*)d_in[11];
  const float* q_w = (const float*)d_in[12],  *q_b = (const float*)d_in[13];
  const float* kv_w = (const float*)d_in[14], *kv_b = (const float*)d_in[15];
  const float* ca_o_w = (const float*)d_in[16], *ca_o_b = (const float*)d_in[17];
  const float* ln3w = (const float*)d_in[18], *ln3b = (const float*)d_in[19];
  const float* ffn_in_w = (const float*)d_in[20], *ffn_in_b = (const float*)d_in[21];
  const float* ffn_out_w = (const float*)d_in[22], *ffn_out_b = (const float*)d_in[23];

  char* ws = (char*)d_ws;
  u16* wt_qkv    = (u16*)(ws + WT_QKV);
  u16* wt_attn_o = (u16*)(ws + WT_ATTN_O);
  u16* wt_q      = (u16*)(ws + WT_Q);
  u16* wt_kv     = (u16*)(ws + WT_KV);
  u16* wt_ca_o   = (u16*)(ws + WT_CA_O);
  u16* wt_ffn_in = (u16*)(ws + WT_FFN_IN);
  u16* wt_ffn_out= (u16*)(ws + WT_FFN_OUT);
  u16* enc_bf = (u16*)(ws + ENC_BF);
  u16* xln    = (u16*)(ws + XLN);
  u16* qh     = (u16*)(ws + QH);
  u16* kh     = (u16*)(ws + KH);
  u16* vht    = (u16*)(ws + VHT);
  u16* ctx    = (u16*)(ws + CTX);
  u16* scores = (u16*)(ws + SCORES);
  float* hF   = (float*)(ws + HBUF);
  float* scratch = (float*)(ws + SCRATCH);
  u16* ffn_mid   = (u16*)(ws + SCRATCH);   // overlays scratch (disjoint lifetime)

  // ---- weight conversion (fp32 [K,N] -> bf16 [N,K]) ----
  wconv_kernel<<<dim3(96, 32), 256, 0, stream>>>(qkv_w, wt_qkv, 1024, 3072);
  wconv_kernel<<<dim3(32, 32), 256, 0, stream>>>(attn_o_w, wt_attn_o, 1024, 1024);
  wconv_kernel<<<dim3(32, 32), 256, 0, stream>>>(q_w, wt_q, 1024, 1024);
  wconv_kernel<<<dim3(64, 32), 256, 0, stream>>>(kv_w, wt_kv, 1024, 2048);
  wconv_kernel<<<dim3(32, 32), 256, 0, stream>>>(ca_o_w, wt_ca_o, 1024, 1024);
  wconv_kernel<<<dim3(128, 32), 256, 0, stream>>>(ffn_in_w, wt_ffn_in, 1024, 4096);
  wconv_kernel<<<dim3(32, 128), 256, 0, stream>>>(ffn_out_w, wt_ffn_out, 4096, 1024);
  cvt_kernel<<<4096, 256, 0, stream>>>(enc, enc_bf);

  // ---- self-attention ----
  ln_kernel<<<4096, 256, 0, stream>>>(hidden, ln1w, ln1b, xln);
  gemm_nt<<<dim3(24, 32, 1), 256, 0, stream>>>(xln, 0, wt_qkv, 0, qkv_b, nullptr,
      scratch, 0, 3072, 4096, 3072, 1024, 0);
  split_qk_kernel<<<dim3(8, 4096), 256, 0, stream>>>(scratch, qh, kh);
  vtrans_kernel<<<dim3(2, 32, 64), 256, 0, stream>>>(scratch, 3072, 2048, vht);
  for (int c = 0; c < 4; ++c) {
    const size_t zb = (size_t)c * 16;
    gemm_nt<<<dim3(8, 8, 16), 256, 0, stream>>>(qh + zb * 65536, 65536LL, kh + zb * 65536, 65536LL,
        nullptr, nullptr, scores, 1048576LL, 1024, 1024, 1024, 64, 1);
    softmax_kernel<<<dim3(1024, 16), 256, 0, stream>>>(scores, nullptr, c * 16, 1);
    gemm_nt<<<dim3(1, 8, 16), 256, 0, stream>>>(scores, 1048576LL, vht + zb * 65536, 65536LL,
        nullptr, nullptr, ctx + (size_t)c * 1048576, 64LL, 1024, 1024, 64, 1024, 1);
  }
  gemm_nt<<<dim3(8, 32, 1), 256, 0, stream>>>(ctx, 0, wt_attn_o, 0, attn_o_b, hidden,
      hF, 0, 1024, 4096, 1024, 1024, 0);

  // ---- cross-attention ----
  ln_kernel<<<4096, 256, 0, stream>>>(hF, ln2w, ln2b, xln);
  gemm_nt<<<dim3(8, 32, 1), 256, 0, stream>>>(xln, 0, wt_q, 0, q_b, nullptr,
      scratch, 0, 1024, 4096, 1024, 1024, 0);
  split_q_kernel<<<dim3(4, 4096), 256, 0, stream>>>(scratch, qh);
  gemm_nt<<<dim3(16, 32, 1), 256, 0, stream>>>(enc_bf, 0, wt_kv, 0, kv_b, nullptr,
      scratch, 0, 2048, 4096, 2048, 1024, 0);
  split_k_kernel<<<dim3(4, 4096), 256, 0, stream>>>(scratch, kh);
  vtrans_kernel<<<dim3(2, 32, 64), 256, 0, stream>>>(scratch, 2048, 1024, vht);
  for (int c = 0; c < 4; ++c) {
    const size_t zb = (size_t)c * 16;
    gemm_nt<<<dim3(8, 8, 16), 256, 0, stream>>>(qh + zb * 65536, 65536LL, kh + zb * 65536, 65536LL,
        nullptr, nullptr, scores, 1048576LL, 1024, 1024, 1024, 64, 1);
    softmax_kernel<<<dim3(1024, 16), 256, 0, stream>>>(scores, encm, c * 16, 0);
    gemm_nt<<<dim3(1, 8, 16), 256, 0, stream>>>(scores, 1048576LL, vht + zb * 65536, 65536LL,
        nullptr, nullptr, ctx + (size_t)c * 1048576, 64LL, 1024, 1024, 64, 1024, 1);
  }
  gemm_nt<<<dim3(8, 32, 1), 256, 0, stream>>>(ctx, 0, wt_ca_o, 0, ca_o_b, hF,
      hF, 0, 1024, 4096, 1024, 1024, 0);   // in-place residual: each thread reads own elem first

  // ---- FFN ----
  ln_kernel<<<4096, 256, 0, stream>>>(hF, ln3w, ln3b, xln);
  gemm_nt<<<dim3(32, 32, 1), 256, 0, stream>>>(xln, 0, wt_ffn_in, 0, ffn_in_b, nullptr,
      ffn_mid, 0, 4096, 4096, 4096, 1024, 2);
  gemm_nt<<<dim3(8, 32, 1), 256, 0, stream>>>(ffn_mid, 0, wt_ffn_out, 0, ffn_out_b, hF,
      (float*)d_out, 0, 1024, 4096, 1024, 4096, 0);
}

// Round 2
// 977.240 us; speedup vs baseline: 1.2950x; 1.2950x over previous
//
#include <hip/hip_runtime.h>
#include <cstdint>
#include <cstddef>

typedef unsigned short u16;
typedef __bf16 bf16x8 __attribute__((ext_vector_type(8)));
typedef float f32x4 __attribute__((ext_vector_type(4)));

// ---------- helpers ----------
__device__ __forceinline__ u16 f2bf(float f) {            // round-to-nearest-even
  unsigned u = __float_as_uint(f);
  u += 0x7fffu + ((u >> 16) & 1u);
  return (u16)(u >> 16);
}
__device__ __forceinline__ float bf2f(u16 s) {
  return __uint_as_float(((unsigned)s) << 16);
}

// async global->LDS, 16B per lane; LDS dest = wave-uniform base + lane*16
// (global source address is fully per-lane — only the LDS side is constrained).
__device__ __forceinline__ void gld16(const void* g, void* l) {
  __builtin_amdgcn_global_load_lds((const __attribute__((address_space(1))) void*)g,
                                   (__attribute__((address_space(3))) void*)l,
                                   16, 0, 0);
}

__device__ __forceinline__ float block_sum(float v, float* sbuf, int tid) {
#pragma unroll
  for (int off = 1; off < 64; off <<= 1) v += __shfl_xor(v, off, 64);
  if ((tid & 63) == 0) sbuf[tid >> 6] = v;
  __syncthreads();
  v = sbuf[0] + sbuf[1] + sbuf[2] + sbuf[3];
  __syncthreads();
  return v;
}

// ---------- generic batched NT GEMM (128x128 tile, BK=32) ----------
// C[z][m][n] = sum_k A[z][m][k] * B[z][n][k]   (both operands K-major)
// mode 0: fp32 out (+bias[n] if bias)(+res[m*ldc+n] if res)
// mode 1: bf16 out
// mode 2: bf16 out = gelu(acc + bias[n])  (exact erf gelu)
__global__ __launch_bounds__(256) void gemm_nt(
    const u16* __restrict__ A, long long sAz,
    const u16* __restrict__ B, long long sBz,
    const float* __restrict__ bias, const float* __restrict__ res,
    void* __restrict__ out, long long sCz, int ldc,
    int M, int N, int K, int mode)
{
  __shared__ __align__(16) u16 As[128 * 32];
  __shared__ __align__(16) u16 Bs[128 * 32];
  const int tid = threadIdx.x;
  const int z = blockIdx.z;
  const u16* Az = A + (size_t)z * (size_t)sAz;
  const u16* Bz = B + (size_t)z * (size_t)sBz;
  const int m0 = blockIdx.y * 128, n0 = blockIdx.x * 128;
  const int lane = tid & 63, wave = tid >> 6;
  const int wm = (wave >> 1) * 64, wn = (wave & 1) * 64;

  const int c0 = tid, c1 = tid + 256;
  const int ar0 = c0 >> 2, ak0 = (c0 & 3) * 8;
  const int ar1 = c1 >> 2, ak1 = (c1 & 3) * 8;
  const size_t aoff0 = (size_t)(m0 + ar0) * K + ak0;
  const size_t aoff1 = (size_t)(m0 + ar1) * K + ak1;
  const size_t boff0 = (size_t)(n0 + ar0) * K + ak0;
  const size_t boff1 = (size_t)(n0 + ar1) * K + ak1;

  f32x4 acc[4][4] = {};

  for (int k0 = 0; k0 < K; k0 += 32) {
    gld16(Az + aoff0 + k0, As + (size_t)c0 * 8);
    gld16(Az + aoff1 + k0, As + (size_t)c1 * 8);
    gld16(Bz + boff0 + k0, Bs + (size_t)c0 * 8);
    gld16(Bz + boff1 + k0, Bs + (size_t)c1 * 8);
    __syncthreads();
    bf16x8 af[4], bg[4];
#pragma unroll
    for (int i = 0; i < 4; i++) {
      af[i] = *(const bf16x8*)(As + (wm + i * 16 + (lane & 15)) * 32 + (lane >> 4) * 8);
      bg[i] = *(const bf16x8*)(Bs + (wn + i * 16 + (lane & 15)) * 32 + (lane >> 4) * 8);
    }
#pragma unroll
    for (int i = 0; i < 4; i++)
#pragma unroll
      for (int j = 0; j < 4; j++)
        acc[i][j] = __builtin_amdgcn_mfma_f32_16x16x32_bf16(af[i], bg[j], acc[i][j], 0, 0, 0);
    __syncthreads();
  }

  float* outF = (float*)out;
  u16* outU = (u16*)out;
  const size_t cbase = (size_t)z * (size_t)sCz;
#pragma unroll
  for (int i = 0; i < 4; i++) {
#pragma unroll
    for (int j = 0; j < 4; j++) {
      const int col = n0 + wn + j * 16 + (lane & 15);
#pragma unroll
      for (int r = 0; r < 4; r++) {
        const int gm = m0 + wm + i * 16 + (lane >> 4) * 4 + r;
        const size_t idx = cbase + (size_t)gm * ldc + col;
        float v = acc[i][j][r];
        if (mode == 0) {
          if (bias) v += bias[col];
          if (res)  v += res[(size_t)gm * ldc + col];
          outF[idx] = v;
        } else if (mode == 1) {
          outU[idx] = f2bf(v);
        } else {
          v += bias[col];
          v = 0.5f * v * (1.0f + erff(v * 0.70710678118654752f));
          outU[idx] = f2bf(v);
        }
      }
    }
  }
}

// ---------- fused flash attention ----------
// qh [64][1024][64] bf16 (pre-scaled 1/8), kh [64][1024][64], vht [64][64][1024]
// ctx out [4][1024][1024] bf16 (merged heads). grid (8 m-tiles, 64 z). 256 thr.
__global__ __launch_bounds__(256) void flash_attn(
    const u16* __restrict__ qh, const u16* __restrict__ kh, const u16* __restrict__ vht,
    const float* __restrict__ emask, u16* __restrict__ ctx, int causal)
{
  __shared__ __align__(16) u16 sK[1024 * 8];   // [dc 0..7][t 0..127][8]  16 KB
  __shared__ __align__(16) u16 sV[1024 * 8];   // [tc 0..15][d 0..63][8]  16 KB
  __shared__ __align__(16) u16 sP[128 * 136];  // P tile, padded stride   34 KB
  __shared__ float sred[2][128];
  __shared__ float srowm[128], srowl[128], salpha[128], smnew[128];

  const int tid = threadIdx.x, lane = tid & 63, wave = tid >> 6;
  const int l15 = lane & 15, g = lane >> 4;
  const int z = blockIdx.y, b = z >> 4, h = z & 15;
  const int m0 = blockIdx.x * 128;
  const int wm = (wave >> 1) * 64, wn = (wave & 1) * 64;

  if (tid < 128) { srowm[tid] = -3.0e38f; srowl[tid] = 0.0f; }

  // Q fragments, register-resident for the whole block
  bf16x8 qf[4][2];
  {
    const u16* qz = qh + ((size_t)z * 1024 + m0 + wm + l15) * 64 + g * 8;
#pragma unroll
    for (int i = 0; i < 4; ++i)
#pragma unroll
      for (int c = 0; c < 2; ++c)
        qf[i][c] = *(const bf16x8*)(qz + (size_t)i * 16 * 64 + c * 32);
  }

  f32x4 o[2][4] = {};   // PV accumulator: rows wave*32..+31, cols d 0..63
  const int tmax = causal ? m0 : 896;

  for (int t0 = 0; t0 <= tmax; t0 += 128) {
    // ---- stage K (t-major, d-chunked) and V (d-major, t-chunked) ----
#pragma unroll
    for (int ii = 0; ii < 4; ++ii) {
      const int c = ii * 256 + tid;
      const int kt = c & 127, dc = c >> 7;
      gld16(kh + ((size_t)z * 1024 + t0 + kt) * 64 + dc * 8, sK + (size_t)c * 8);
      const int vd = c & 63, tc = c >> 6;
      gld16(vht + ((size_t)z * 64 + vd) * 1024 + t0 + tc * 8, sV + (size_t)c * 8);
    }
    __syncthreads();

    // ---- S = Q K^T : wave covers rows [wm,wm+64) x cols [wn,wn+64) ----
    f32x4 sa[4][4] = {};
#pragma unroll
    for (int kc = 0; kc < 2; ++kc) {
      bf16x8 bg[4];
#pragma unroll
      for (int jn = 0; jn < 4; ++jn)
        bg[jn] = *(const bf16x8*)(sK + ((size_t)(kc * 4 + g) * 128 + wn + jn * 16 + l15) * 8);
#pragma unroll
      for (int i = 0; i < 4; ++i)
#pragma unroll
        for (int jn = 0; jn < 4; ++jn)
          sa[i][jn] = __builtin_amdgcn_mfma_f32_16x16x32_bf16(qf[i][kc], bg[jn], sa[i][jn], 0, 0, 0);
    }

    // ---- mask ----
    if (causal) {
      if (t0 == m0) {           // only the diagonal tile needs masking
#pragma unroll
        for (int i = 0; i < 4; ++i)
#pragma unroll
          for (int jn = 0; jn < 4; ++jn) {
            const int col = wn + jn * 16 + l15;
#pragma unroll
            for (int r = 0; r < 4; ++r) {
              const int row_l = wm + i * 16 + g * 4 + r;
              if (col > row_l) sa[i][jn][r] = -3.0e38f;
            }
          }
      }
    } else {
#pragma unroll
      for (int jn = 0; jn < 4; ++jn) {
        const float mv = emask[(size_t)b * 1024 + t0 + wn + jn * 16 + l15];
#pragma unroll
        for (int i = 0; i < 4; ++i)
#pragma unroll
          for (int r = 0; r < 4; ++r) sa[i][jn][r] += mv;
      }
    }

    // ---- per-row tile max (16-lane shuffle + cross-wave via LDS) ----
#pragma unroll
    for (int i = 0; i < 4; ++i)
#pragma unroll
      for (int r = 0; r < 4; ++r) {
        float v = fmaxf(fmaxf(sa[i][0][r], sa[i][1][r]), fmaxf(sa[i][2][r], sa[i][3][r]));
        v = fmaxf(v, __shfl_xor(v, 1, 64));
        v = fmaxf(v, __shfl_xor(v, 2, 64));
        v = fmaxf(v, __shfl_xor(v, 4, 64));
        v = fmaxf(v, __shfl_xor(v, 8, 64));
        if (l15 == 0) sred[wave & 1][wm + i * 16 + g * 4 + r] = v;
      }
    __syncthreads();

    if (tid < 128) {
      const float tm = fmaxf(sred[0][tid], sred[1][tid]);
      const float mo = srowm[tid];
      const float mn = fmaxf(mo, tm);
      srowm[tid] = mn; smnew[tid] = mn;
      salpha[tid] = __expf(mo - mn);     // first iter: exp(-3e38-mn) -> 0
    }
    __syncthreads();

    // ---- P = exp(S - mnew), partial sums, write P tile to LDS ----
#pragma unroll
    for (int i = 0; i < 4; ++i)
#pragma unroll
      for (int r = 0; r < 4; ++r) {
        const int row_l = wm + i * 16 + g * 4 + r;
        const float mn = smnew[row_l];
        float s = 0.f;
#pragma unroll
        for (int jn = 0; jn < 4; ++jn) {
          const float p = __expf(sa[i][jn][r] - mn);
          s += p;
          sP[(size_t)row_l * 136 + wn + jn * 16 + l15] = f2bf(p);
        }
        s += __shfl_xor(s, 1, 64);
        s += __shfl_xor(s, 2, 64);
        s += __shfl_xor(s, 4, 64);
        s += __shfl_xor(s, 8, 64);
        if (l15 == 0) sred[wave & 1][row_l] = s;
      }
    __syncthreads();

    if (tid < 128)
      srowl[tid] = salpha[tid] * srowl[tid] + sred[0][tid] + sred[1][tid];

    // ---- O = alpha*O + P V : wave handles rows [wave*32, +32) x d[0,64) ----
    float al[2][4];
#pragma unroll
    for (int i2 = 0; i2 < 2; ++i2)
#pragma unroll
      for (int r = 0; r < 4; ++r)
        al[i2][r] = salpha[wave * 32 + i2 * 16 + g * 4 + r];
#pragma unroll
    for (int i2 = 0; i2 < 2; ++i2)
#pragma unroll
      for (int jn = 0; jn < 4; ++jn)
#pragma unroll
        for (int r = 0; r < 4; ++r)
          o[i2][jn][r] *= al[i2][r];
#pragma unroll
    for (int kc = 0; kc < 4; ++kc) {
      bf16x8 pa[2], vb[4];
#pragma unroll
      for (int i2 = 0; i2 < 2; ++i2)
        pa[i2] = *(const bf16x8*)(sP + (size_t)(wave * 32 + i2 * 16 + l15) * 136 + kc * 32 + g * 8);
#pragma unroll
      for (int jn = 0; jn < 4; ++jn)
        vb[jn] = *(const bf16x8*)(sV + ((size_t)(kc * 4 + g) * 64 + jn * 16 + l15) * 8);
#pragma unroll
      for (int i2 = 0; i2 < 2; ++i2)
#pragma unroll
        for (int jn = 0; jn < 4; ++jn)
          o[i2][jn] = __builtin_amdgcn_mfma_f32_16x16x32_bf16(pa[i2], vb[jn], o[i2][jn], 0, 0, 0);
    }
    __syncthreads();   // protect sK/sV/sP before next staging
  }

  // ---- epilogue: O / l, write merged-heads ctx ----
#pragma unroll
  for (int i2 = 0; i2 < 2; ++i2) {
#pragma unroll
    for (int r = 0; r < 4; ++r) {
      const int row_l = wave * 32 + i2 * 16 + g * 4 + r;
      const float inv = 1.0f / srowl[row_l];
      const size_t base = ((size_t)(b * 1024 + m0 + row_l)) * 1024 + h * 64;
#pragma unroll
      for (int jn = 0; jn < 4; ++jn)
        ctx[base + jn * 16 + l15] = f2bf(o[i2][jn][r] * inv);
    }
  }
}

// ---------- layernorm (row=1024) -> bf16 ----------
__global__ __launch_bounds__(256) void ln_kernel(const float* __restrict__ x,
    const float* __restrict__ w, const float* __restrict__ b, u16* __restrict__ out)
{
  __shared__ float sbuf[4];
  const int row = blockIdx.x, tid = threadIdx.x;
  const float4 v = *(const float4*)(x + (size_t)row * 1024 + tid * 4);
  float s = block_sum(v.x + v.y + v.z + v.w, sbuf, tid);
  const float u = s * (1.0f / 1024.0f);
  const float d0 = v.x - u, d1 = v.y - u, d2 = v.z - u, d3 = v.w - u;
  float sq = block_sum(d0 * d0 + d1 * d1 + d2 * d2 + d3 * d3, sbuf, tid);
  const float rstd = rsqrtf(sq * (1.0f / 1024.0f) + 1e-12f);
  const int c = tid * 4;
  ushort4 o;
  o.x = f2bf(w[c + 0] * d0 * rstd + b[c + 0]);
  o.y = f2bf(w[c + 1] * d1 * rstd + b[c + 1]);
  o.z = f2bf(w[c + 2] * d2 * rstd + b[c + 2]);
  o.w = f2bf(w[c + 3] * d3 * rstd + b[c + 3]);
  *(ushort4*)(out + (size_t)row * 1024 + c) = o;
}

// ---------- weight fp32[K,N] -> bf16 transposed [N,K] ----------
__global__ __launch_bounds__(256) void wconv_kernel(const float* __restrict__ w,
    u16* __restrict__ wt, int K, int N)
{
  __shared__ float t[32][33];
  const int n0 = blockIdx.x * 32, k0 = blockIdx.y * 32;
  const int tx = threadIdx.x & 31, ty = threadIdx.x >> 5;
#pragma unroll
  for (int r = ty; r < 32; r += 8) t[r][tx] = w[(size_t)(k0 + r) * N + n0 + tx];
  __syncthreads();
#pragma unroll
  for (int r = ty; r < 32; r += 8) wt[(size_t)(n0 + r) * K + k0 + tx] = f2bf(t[tx][r]);
}

// ---------- fp32 -> bf16 elementwise ----------
__global__ __launch_bounds__(256) void cvt_kernel(const float* __restrict__ in, u16* __restrict__ out) {
  const size_t i = ((size_t)blockIdx.x * 256 + threadIdx.x) * 4;
  const float4 v = *(const float4*)(in + i);
  ushort4 o; o.x = f2bf(v.x); o.y = f2bf(v.y); o.z = f2bf(v.z); o.w = f2bf(v.w);
  *(ushort4*)(out + i) = o;
}

// ---------- head-split kernels ----------
__global__ __launch_bounds__(256) void split_qk_kernel(const float* __restrict__ src,
    u16* __restrict__ qh, u16* __restrict__ kh)
{
  const int n = blockIdx.x * 256 + threadIdx.x;  // 0..2047
  const int m = blockIdx.y;                      // 0..4095
  const float v = src[(size_t)m * 3072 + n];
  const int which = n >> 10, r = n & 1023, h = r >> 6, d = r & 63;
  const int b = m >> 10, s = m & 1023;
  const size_t o = ((size_t)((b * 16 + h) * 1024 + s)) * 64 + d;
  if (which == 0) qh[o] = f2bf(v * 0.125f);
  else            kh[o] = f2bf(v);
}
__global__ __launch_bounds__(256) void split_q_kernel(const float* __restrict__ src, u16* __restrict__ qh) {
  const int n = blockIdx.x * 256 + threadIdx.x;
  const int m = blockIdx.y;
  const int h = n >> 6, d = n & 63, b = m >> 10, s = m & 1023;
  qh[((size_t)((b * 16 + h) * 1024 + s)) * 64 + d] = f2bf(src[(size_t)m * 1024 + n] * 0.125f);
}
__global__ __launch_bounds__(256) void split_k_kernel(const float* __restrict__ src, u16* __restrict__ kh) {
  const int n = blockIdx.x * 256 + threadIdx.x;
  const int m = blockIdx.y;
  const int h = n >> 6, d = n & 63, b = m >> 10, s = m & 1023;
  kh[((size_t)((b * 16 + h) * 1024 + s)) * 64 + d] = f2bf(src[(size_t)m * 2048 + n]);
}
__global__ __launch_bounds__(256) void vtrans_kernel(const float* __restrict__ src,
    int src_ld, int col_off, u16* __restrict__ vht)
{
  __shared__ float t[32][33];
  const int z = blockIdx.z, b = z >> 4, h = z & 15;
  const int s0 = blockIdx.y * 32, d0 = blockIdx.x * 32;
  const int tx = threadIdx.x & 31, ty = threadIdx.x >> 5;
#pragma unroll
  for (int r = ty; r < 32; r += 8)
    t[r][tx] = src[(size_t)(b * 1024 + s0 + r) * src_ld + col_off + h * 64 + d0 + tx];
  __syncthreads();
#pragma unroll
  for (int r = ty; r < 32; r += 8)
    vht[((size_t)z * 64 + d0 + r) * 1024 + s0 + tx] = f2bf(t[tx][r]);
}

// ---------- workspace layout (bytes) ----------
constexpr size_t WT_QKV    = 0;
constexpr size_t WT_ATTN_O = WT_QKV    + 3072ULL * 1024 * 2;
constexpr size_t WT_Q      = WT_ATTN_O + 1024ULL * 1024 * 2;
constexpr size_t WT_KV     = WT_Q      + 1024ULL * 1024 * 2;
constexpr size_t WT_CA_O   = WT_KV     + 2048ULL * 1024 * 2;
constexpr size_t WT_FFN_IN = WT_CA_O   + 1024ULL * 1024 * 2;
constexpr size_t WT_FFN_OUT= WT_FFN_IN + 4096ULL * 1024 * 2;
constexpr size_t ENC_BF    = WT_FFN_OUT+ 4096ULL * 1024 * 2;
constexpr size_t XLN       = ENC_BF    + 4096ULL * 1024 * 2;
constexpr size_t QH        = XLN       + 4096ULL * 1024 * 2;
constexpr size_t KH        = QH        + 64ULL * 1024 * 64 * 2;
constexpr size_t VHT       = KH        + 64ULL * 1024 * 64 * 2;
constexpr size_t CTX       = VHT       + 64ULL * 1024 * 64 * 2;
constexpr size_t SCORES    = CTX       + 4096ULL * 1024 * 2;          // (unused now)
constexpr size_t HBUF      = SCORES    + 16ULL * 1024 * 1024 * 2;
constexpr size_t SCRATCH   = HBUF      + 4096ULL * 1024 * 4;

extern "C" void kernel_launch(void* const* d_in, const int* in_sizes, int n_in,
                              void* d_out, int out_size, void* d_ws, size_t ws_size,
                              hipStream_t stream) {
  const float* hidden   = (const float*)d_in[0];
  const float* enc      = (const float*)d_in[1];
  const float* encm     = (const float*)d_in[2];
  const float* ln1w = (const float*)d_in[4],  *ln1b = (const float*)d_in[5];
  const float* qkv_w = (const float*)d_in[6], *qkv_b = (const float*)d_in[7];
  const float* attn_o_w = (const float*)d_in[8], *attn_o_b = (const float*)d_in[9];
  const float* ln2w = (const float*)d_in[10], *ln2b = (const float*)d_in[11];
  const float* q_w = (const float*)d_in[12],  *q_b = (const float*)d_in[13];
  const float* kv_w = (const float*)d_in[14], *kv_b = (const float*)d_in[15];
  const float* ca_o_w = (const float*)d_in[16], *ca_o_b = (const float*)d_in[17];
  const float* ln3w = (const float*)d_in[18], *ln3b = (const float*)d_in[19];
  const float* ffn_in_w = (const float*)d_in[20], *ffn_in_b = (const float*)d_in[21];
  const float* ffn_out_w = (const float*)d_in[22], *ffn_out_b = (const float*)d_in[23];

  char* ws = (char*)d_ws;
  u16* wt_qkv    = (u16*)(ws + WT_QKV);
  u16* wt_attn_o = (u16*)(ws + WT_ATTN_O);
  u16* wt_q      = (u16*)(ws + WT_Q);
  u16* wt_kv     = (u16*)(ws + WT_KV);
  u16* wt_ca_o   = (u16*)(ws + WT_CA_O);
  u16* wt_ffn_in = (u16*)(ws + WT_FFN_IN);
  u16* wt_ffn_out= (u16*)(ws + WT_FFN_OUT);
  u16* enc_bf = (u16*)(ws + ENC_BF);
  u16* xln    = (u16*)(ws + XLN);
  u16* qh     = (u16*)(ws + QH);
  u16* kh     = (u16*)(ws + KH);
  u16* vht    = (u16*)(ws + VHT);
  u16* ctx    = (u16*)(ws + CTX);
  float* hF   = (float*)(ws + HBUF);
  float* scratch = (float*)(ws + SCRATCH);
  u16* ffn_mid   = (u16*)(ws + SCRATCH);   // overlays scratch (disjoint lifetime)

  // ---- weight conversion ----
  wconv_kernel<<<dim3(96, 32), 256, 0, stream>>>(qkv_w, wt_qkv, 1024, 3072);
  wconv_kernel<<<dim3(32, 32), 256, 0, stream>>>(attn_o_w, wt_attn_o, 1024, 1024);
  wconv_kernel<<<dim3(32, 32), 256, 0, stream>>>(q_w, wt_q, 1024, 1024);
  wconv_kernel<<<dim3(64, 32), 256, 0, stream>>>(kv_w, wt_kv, 1024, 2048);
  wconv_kernel<<<dim3(32, 32), 256, 0, stream>>>(ca_o_w, wt_ca_o, 1024, 1024);
  wconv_kernel<<<dim3(128, 32), 256, 0, stream>>>(ffn_in_w, wt_ffn_in, 1024, 4096);
  wconv_kernel<<<dim3(32, 128), 256, 0, stream>>>(ffn_out_w, wt_ffn_out, 4096, 1024);
  cvt_kernel<<<4096, 256, 0, stream>>>(enc, enc_bf);

  // ---- self-attention ----
  ln_kernel<<<4096, 256, 0, stream>>>(hidden, ln1w, ln1b, xln);
  gemm_nt<<<dim3(24, 32, 1), 256, 0, stream>>>(xln, 0, wt_qkv, 0, qkv_b, nullptr,
      scratch, 0, 3072, 4096, 3072, 1024, 0);
  split_qk_kernel<<<dim3(8, 4096), 256, 0, stream>>>(scratch, qh, kh);
  vtrans_kernel<<<dim3(2, 32, 64), 256, 0, stream>>>(scratch, 3072, 2048, vht);
  flash_attn<<<dim3(8, 64), 256, 0, stream>>>(qh, kh, vht, nullptr, ctx, 1);
  gemm_nt<<<dim3(8, 32, 1), 256, 0, stream>>>(ctx, 0, wt_attn_o, 0, attn_o_b, hidden,
      hF, 0, 1024, 4096, 1024, 1024, 0);

  // ---- cross-attention ----
  ln_kernel<<<4096, 256, 0, stream>>>(hF, ln2w, ln2b, xln);
  gemm_nt<<<dim3(8, 32, 1), 256, 0, stream>>>(xln, 0, wt_q, 0, q_b, nullptr,
      scratch, 0, 1024, 4096, 1024, 1024, 0);
  split_q_kernel<<<dim3(4, 4096), 256, 0, stream>>>(scratch, qh);
  gemm_nt<<<dim3(16, 32, 1), 256, 0, stream>>>(enc_bf, 0, wt_kv, 0, kv_b, nullptr,
      scratch, 0, 2048, 4096, 2048, 1024, 0);
  split_k_kernel<<<dim3(4, 4096), 256, 0, stream>>>(scratch, kh);
  vtrans_kernel<<<dim3(2, 32, 64), 256, 0, stream>>>(scratch, 2048, 1024, vht);
  flash_attn<<<dim3(8, 64), 256, 0, stream>>>(qh, kh, vht, encm, ctx, 0);
  gemm_nt<<<dim3(8, 32, 1), 256, 0, stream>>>(ctx, 0, wt_ca_o, 0, ca_o_b, hF,
      hF, 0, 1024, 4096, 1024, 1024, 0);

  // ---- FFN ----
  ln_kernel<<<4096, 256, 0, stream>>>(hF, ln3w, ln3b, xln);
  gemm_nt<<<dim3(32, 32, 1), 256, 0, stream>>>(xln, 0, wt_ffn_in, 0, ffn_in_b, nullptr,
      ffn_mid, 0, 4096, 4096, 4096, 1024, 2);
  gemm_nt<<<dim3(8, 32, 1), 256, 0, stream>>>(ffn_mid, 0, wt_ffn_out, 0, ffn_out_b, hF,
      (float*)d_out, 0, 1024, 4096, 1024, 4096, 0);
}